// Round 11
// baseline (233.993 us; speedup 1.0000x reference)
//
#include <hip/hip_runtime.h>

typedef __bf16    bf16x8 __attribute__((ext_vector_type(8)));
typedef __bf16    bf16x4 __attribute__((ext_vector_type(4)));
typedef float     f32x4  __attribute__((ext_vector_type(4)));

#define BM 128
#define BN 128
#define BK 64

// async global->LDS, 16B per lane. LDS dest must be wave-uniform base + lane*16.
__device__ __forceinline__ void gload_lds16(const __bf16* g, __bf16* l) {
  __builtin_amdgcn_global_load_lds(
      (const __attribute__((address_space(1))) void*)g,
      (__attribute__((address_space(3))) void*)l,
      16, 0, 0);
}

// ============================================================================
// SESSION LEDGER (rounds 0-10), so future edits don't re-litigate:
//  - 256^2 8-phase port (r1-r3): conflict-free but ~= 128^2 perf; my port
//    deviates from m201 (K-half slots vs M-half 128B-row geometry) — only a
//    FAITHFUL re-port is worth trying again.
//  - 32x32x16 MFMA swap (r4): +4.19M conflict-cycles, -22%. Do NOT switch
//    MFMA shape without re-measuring conflicts.
//  - proj merge QK+VT (r5): VERIFIED WIN (47+24+gap -> 59-60us).
//  - persistent fusion (r6-r8): cg::sync = wrong answers; hand barrier =
//    correct but uniformly 2.2x slower (same MFMA-busy, same HBM bytes);
//    RMW-spin theory FALSIFIED by relaxed-load A/B. ABANDONED.
//  - r10 reg-bucket: arch 72->64 (saddr+voffset staging + bounds(256,4)) ->
//    136->128 unified regs -> 16 waves/CU bucket. VERIFIED WIN 245->228;
//    scores/PV dropped ~47 -> ~40us (below top-5 cutoff). scores now at the
//    documented m97-structure ceiling (~860 TF).
//  - r11: PV retile 128x64 -> 1024 blocks (fill the 4-deep residency PV's
//    512-block grid leaves half-empty).
// ============================================================================

// One launch converts x (8192 blocks) + Wq/Wk/Wv (3072 blocks) to bf16.
// Block 0 additionally zero-inits the row-sum accumulator.
__global__ void cvt_all(const float* __restrict__ x, const float* __restrict__ Wq,
                        const float* __restrict__ Wk, const float* __restrict__ Wv,
                        __bf16* __restrict__ xb, __bf16* __restrict__ Wqk,
                        __bf16* __restrict__ Wvb, float* __restrict__ lsum) {
  int b = blockIdx.x;
  if (b == 0) {
    for (int j = threadIdx.x; j < 8192; j += 256) lsum[j] = 0.f;
  }
  const float* src;
  __bf16* dst;
  int i;
  if (b < 8192) {
    src = x; dst = xb; i = b * 256 + threadIdx.x;
  } else {
    b -= 8192;
    const int mat = b >> 10;
    i = (b & 1023) * 256 + threadIdx.x;
    src = (mat == 0) ? Wq : (mat == 1) ? Wk : Wv;
    dst = (mat == 0) ? Wqk : (mat == 1) ? (Wqk + 1048576) : Wvb;
  }
  float4 v = ((const float4*)src)[i];
  bf16x4 o;
  o[0] = (__bf16)v.x; o[1] = (__bf16)v.y; o[2] = (__bf16)v.z; o[3] = (__bf16)v.w;
  ((bf16x4*)dst)[i] = o;
}

// ============================================================================
// PROVEN inner structure (16x16x32, 0 bank conflicts, ~860 TF at 4 blk/CU).
// LDS tiles: 16B slot g' of row r holds global k-group (g' ^ (r&7)), swizzle
// applied on the GLOBAL SOURCE address (gload_lds dest must stay linear).
// R10 ADDRESSING: staging address = uniform base (SGPR) + one int voffset.
// ============================================================================
__device__ __forceinline__ void gemm_core(
    const __bf16* __restrict__ A, const __bf16* __restrict__ B,
    int lda, int ldb, int K, int bm0, int bn0,
    int tid, int wm, int wn, int quad, int l15,
    __bf16* As, __bf16* Bs, f32x4 (&acc)[4][4])
{
  const int rr  = tid >> 3;                       // staging row within chunk
  const int gsl = ((tid & 7) ^ (rr & 7)) * 8;     // swizzled 16B-slot (elems)
  const int voA = rr * lda + gsl;                 // lane-varying, fits int
  const int voB = rr * ldb + gsl;

  for (int k0 = 0; k0 < K; k0 += BK) {
#pragma unroll
    for (int c = 0; c < 4; ++c) {
      gload_lds16(A + (size_t)(bm0 + c * 32) * lda + k0 + voA,
                  &As[c * 2048 + tid * 8]);
      gload_lds16(B + (size_t)(bn0 + c * 32) * ldb + k0 + voB,
                  &Bs[c * 2048 + tid * 8]);
    }
    __syncthreads();

#pragma unroll
    for (int kk = 0; kk < 2; ++kk) {
      bf16x8 af[4], bfv[4];
#pragma unroll
      for (int i = 0; i < 4; ++i) {
        const int R = wm + i * 16 + l15;
        af[i] = *(const bf16x8*)&As[R * BK + (((kk * 4 + quad) ^ (R & 7)) * 8)];
      }
#pragma unroll
      for (int i = 0; i < 4; ++i) {
        const int R = wn + i * 16 + l15;
        bfv[i] = *(const bf16x8*)&Bs[R * BK + (((kk * 4 + quad) ^ (R & 7)) * 8)];
      }
#pragma unroll
      for (int mi = 0; mi < 4; ++mi)
#pragma unroll
        for (int ni = 0; ni < 4; ++ni)
          acc[mi][ni] = __builtin_amdgcn_mfma_f32_16x16x32_bf16(
              af[mi], bfv[ni], acc[mi][ni], 0, 0, 0);
    }
    __syncthreads();
  }
}

// ============================================================================
// Merged projection launch (VERIFIED: ~60us).
//  blocks [0,1024):  QK  — xb[8192,1024] @ Wqk[2048,1024]^T -> Q,K (+bias)
//  blocks [1024,1536): VT — Wvb[1024,1024] @ xb[8192,1024]^T -> Vt (+bias[gm])
// ============================================================================
__global__ __launch_bounds__(256, 4)
void proj_qkv(const __bf16* __restrict__ xb, const __bf16* __restrict__ Wqk,
              const __bf16* __restrict__ Wvb,
              const float* __restrict__ bq, const float* __restrict__ bk,
              const float* __restrict__ bv,
              __bf16* __restrict__ Q, __bf16* __restrict__ Kb,
              __bf16* __restrict__ Vt)
{
  const int bid  = blockIdx.x;
  const int tid  = threadIdx.x;
  const int wave = tid >> 6;
  const int lane = tid & 63;
  const int quad = lane >> 4;
  const int l15  = lane & 15;
  const int wm   = (wave >> 1) * 64;
  const int wn   = (wave & 1) * 64;

  const bool isQK = bid < 1024;
  const __bf16* A;
  const __bf16* B;
  int bm0, bn0;
  if (isQK) {                       // grid 64 (M) x 16 (N)
    A = xb;  B = Wqk;
    bm0 = (bid & 63) * BM;  bn0 = (bid >> 6) * BN;
  } else {                          // grid 8 (M) x 64 (N)
    const int b2 = bid - 1024;
    A = Wvb; B = xb;
    bm0 = (b2 & 7) * BM;    bn0 = (b2 >> 3) * BN;
  }

  __shared__ __align__(16) __bf16 As[BM * BK];   // 16 KB
  __shared__ __align__(16) __bf16 Bs[BN * BK];   // 16 KB

  f32x4 acc[4][4];
#pragma unroll
  for (int i = 0; i < 4; ++i)
#pragma unroll
    for (int j = 0; j < 4; ++j)
      acc[i][j] = (f32x4){0.f, 0.f, 0.f, 0.f};

  gemm_core(A, B, 1024, 1024, 1024, bm0, bn0, tid, wm, wn, quad, l15,
            As, Bs, acc);

  // Epilogue. C/D layout (verified m89/m91): row m = quad*4+r, col n = lane&15.
  if (isQK) {
#pragma unroll
    for (int mi = 0; mi < 4; ++mi) {
#pragma unroll
      for (int ni = 0; ni < 4; ++ni) {
        const int gn  = bn0 + wn + ni * 16 + l15;
        const int mat = gn >> 10;          // uniform per tile
        const int d   = gn & 1023;
        const float* bias = (mat == 0) ? bq : bk;
        __bf16* dst = (mat == 0) ? Q : Kb;
        const float bvv = bias[d];
#pragma unroll
        for (int r = 0; r < 4; ++r) {
          const int gm = bm0 + wm + mi * 16 + quad * 4 + r;
          dst[(size_t)gm * 1024 + d] = (__bf16)(acc[mi][ni][r] + bvv);
        }
      }
    }
  } else {  // VT: out Vt[b][gm][s], gn = b*2048 + s, bias bv[gm]
#pragma unroll
    for (int mi = 0; mi < 4; ++mi) {
#pragma unroll
      for (int ni = 0; ni < 4; ++ni) {
        const int gn = bn0 + wn + ni * 16 + l15;
        const int b  = gn >> 11, s = gn & 2047;
#pragma unroll
        for (int r = 0; r < 4; ++r) {
          const int gm = bm0 + wm + mi * 16 + quad * 4 + r;
          Vt[(size_t)b * (1024 * 2048) + (size_t)gm * 2048 + s] =
              (__bf16)(acc[mi][ni][r] + bv[gm]);
        }
      }
    }
  }
}

// ============================================================================
// scores kernel (proven 128x128 structure).
// ============================================================================
__global__ __launch_bounds__(256, 4)
void gemm_sc(const __bf16* __restrict__ A, const __bf16* __restrict__ B,
             int lda, int ldb, int ldc, int K,
             long sA, long sB, long sC,
             float* __restrict__ lsum,
             __bf16* __restrict__ out0)
{
  A += (long)blockIdx.z * sA;
  B += (long)blockIdx.z * sB;

  const int tid  = threadIdx.x;
  const int wave = tid >> 6;
  const int lane = tid & 63;
  const int quad = lane >> 4;
  const int l15  = lane & 15;
  const int bm0  = blockIdx.x * BM;
  const int bn0  = blockIdx.y * BN;
  const int wm   = (wave >> 1) * 64;
  const int wn   = (wave & 1) * 64;

  __shared__ __align__(16) __bf16 As[BM * BK];   // 16 KB
  __shared__ __align__(16) __bf16 Bs[BN * BK];   // 16 KB

  f32x4 acc[4][4];
#pragma unroll
  for (int i = 0; i < 4; ++i)
#pragma unroll
    for (int j = 0; j < 4; ++j)
      acc[i][j] = (f32x4){0.f, 0.f, 0.f, 0.f};

  gemm_core(A, B, lda, ldb, K, bm0, bn0, tid, wm, wn, quad, l15,
            As, Bs, acc);

  // scores: w = exp(v/32) -> bf16; row sums into lsum via shfl+atomic.
#pragma unroll
  for (int mi = 0; mi < 4; ++mi) {
#pragma unroll
    for (int r = 0; r < 4; ++r) {
      const int gm = bm0 + wm + mi * 16 + quad * 4 + r;
      float part = 0.f;
#pragma unroll
      for (int ni = 0; ni < 4; ++ni) {
        const int gn = bn0 + wn + ni * 16 + l15;
        const __bf16 eb = (__bf16)__expf(acc[mi][ni][r] * 0.03125f);
        out0[(long)blockIdx.z * sC + (size_t)gm * ldc + gn] = eb;
        part += (float)eb;  // sum the rounded values PV will actually read
      }
      part += __shfl_xor(part, 1);
      part += __shfl_xor(part, 2);
      part += __shfl_xor(part, 4);
      part += __shfl_xor(part, 8);
      if (l15 == 0)
        atomicAdd(&lsum[blockIdx.z * 2048 + gm], part);
    }
  }
}

// ============================================================================
// R11 PV kernel: 128x64 tile -> 1024 blocks (grid 16x16x4) so the 4-deep
// residency unlocked in r10 is fully used (old 512-block grid = 2 blk/CU of
// work = half the wave-slots idle). 4 waves 2Mx2N, per-wave 64x32, acc[4][2]
// (32 regs -> ~96 total, same 128 bucket). B tile 64x64 = 8KB (2 chunks).
// Same proven swizzle on both A (128-row) and B (64-row) tiles.
// ============================================================================
__global__ __launch_bounds__(256, 4)
void gemm_pv(const __bf16* __restrict__ A, const __bf16* __restrict__ B,
             float* __restrict__ C,
             int lda, int ldb, int ldc, int K,
             long sA, long sB, long sC,
             const float* __restrict__ lsum)
{
  A += (long)blockIdx.z * sA;
  B += (long)blockIdx.z * sB;

  const int tid  = threadIdx.x;
  const int wave = tid >> 6;
  const int lane = tid & 63;
  const int quad = lane >> 4;
  const int l15  = lane & 15;
  const int bm0  = blockIdx.x * 128;
  const int bn0  = blockIdx.y * 64;
  const int wm   = (wave >> 1) * 64;   // 2 M-waves
  const int wn   = (wave & 1) * 32;    // 2 N-waves

  __shared__ __align__(16) __bf16 As[128 * BK];  // 16 KB
  __shared__ __align__(16) __bf16 Bs[64 * BK];   //  8 KB

  f32x4 acc[4][2];
#pragma unroll
  for (int i = 0; i < 4; ++i)
#pragma unroll
    for (int j = 0; j < 2; ++j)
      acc[i][j] = (f32x4){0.f, 0.f, 0.f, 0.f};

  const int rr  = tid >> 3;
  const int gsl = ((tid & 7) ^ (rr & 7)) * 8;
  const int voA = rr * lda + gsl;
  const int voB = rr * ldb + gsl;

  for (int k0 = 0; k0 < K; k0 += BK) {
#pragma unroll
    for (int c = 0; c < 4; ++c)
      gload_lds16(A + (size_t)(bm0 + c * 32) * lda + k0 + voA,
                  &As[c * 2048 + tid * 8]);
#pragma unroll
    for (int c = 0; c < 2; ++c)
      gload_lds16(B + (size_t)(bn0 + c * 32) * ldb + k0 + voB,
                  &Bs[c * 2048 + tid * 8]);
    __syncthreads();

#pragma unroll
    for (int kk = 0; kk < 2; ++kk) {
      bf16x8 af[4], bfv[2];
#pragma unroll
      for (int i = 0; i < 4; ++i) {
        const int R = wm + i * 16 + l15;
        af[i] = *(const bf16x8*)&As[R * BK + (((kk * 4 + quad) ^ (R & 7)) * 8)];
      }
#pragma unroll
      for (int i = 0; i < 2; ++i) {
        const int R = wn + i * 16 + l15;
        bfv[i] = *(const bf16x8*)&Bs[R * BK + (((kk * 4 + quad) ^ (R & 7)) * 8)];
      }
#pragma unroll
      for (int mi = 0; mi < 4; ++mi)
#pragma unroll
        for (int ni = 0; ni < 2; ++ni)
          acc[mi][ni] = __builtin_amdgcn_mfma_f32_16x16x32_bf16(
              af[mi], bfv[ni], acc[mi][ni], 0, 0, 0);
    }
    __syncthreads();
  }

  // PV epilogue: normalize by row sum while storing fp32.
#pragma unroll
  for (int mi = 0; mi < 4; ++mi) {
#pragma unroll
    for (int r = 0; r < 4; ++r) {
      const int gm = bm0 + wm + mi * 16 + quad * 4 + r;
      const float rv = 1.0f / lsum[blockIdx.z * 2048 + gm];
#pragma unroll
      for (int ni = 0; ni < 2; ++ni) {
        const int gn = bn0 + wn + ni * 16 + l15;
        C[(long)blockIdx.z * sC + (size_t)gm * ldc + gn] = acc[mi][ni][r] * rv;
      }
    }
  }
}

extern "C" void kernel_launch(void* const* d_in, const int* in_sizes, int n_in,
                              void* d_out, int out_size, void* d_ws, size_t ws_size,
                              hipStream_t stream) {
  const float* x  = (const float*)d_in[0];
  const float* Wq = (const float*)d_in[1];
  const float* bq = (const float*)d_in[2];
  const float* Wk = (const float*)d_in[3];
  const float* bk = (const float*)d_in[4];
  const float* Wv = (const float*)d_in[5];
  const float* bv = (const float*)d_in[6];
  float* out = (float*)d_out;

  // ws layout:
  //  [0,16M)    Q    bf16 [8192][1024]
  //  [16,32M)   K    bf16 [8192][1024]
  //  [32,48M)   Vt   bf16 [4][1024][2048]
  //  [48,64M)   xb   bf16 (projection phase only)
  //  [64,68M)   Wqk  bf16 [2048][1024] (projection phase only)
  //  [68,70M)   Wvb  bf16 [1024][1024] (projection phase only)
  //  [48,80M)   Sc   bf16 [4][2048][2048] exp-weights (aliases xb/Wqk/Wvb)
  //  [110M,+32K) lsum fp32 [8192] row sums (zeroed by cvt_all block 0)
  char* ws = (char*)d_ws;
  __bf16* Q    = (__bf16*)(ws);
  __bf16* Kb   = (__bf16*)(ws + (16ull << 20));
  __bf16* Vt   = (__bf16*)(ws + (32ull << 20));
  __bf16* xb   = (__bf16*)(ws + (48ull << 20));
  __bf16* Wqk  = (__bf16*)(ws + (64ull << 20));
  __bf16* Wvb  = (__bf16*)(ws + (68ull << 20));
  __bf16* Sc   = (__bf16*)(ws + (48ull << 20));
  float*  lsum = (float*)(ws + (110ull << 20));

  dim3 blk(256);

  // fp32 -> bf16 (+ lsum zero-init), one launch
  cvt_all<<<11264, blk, 0, stream>>>(x, Wq, Wk, Wv, xb, Wqk, Wvb, lsum);

  // Merged QK + VT projection (independent outputs, shared structure)
  proj_qkv<<<1536, blk, 0, stream>>>(xb, Wqk, Wvb, bq, bk, bv, Q, Kb, Vt);

  // scores: per batch Q[2048,1024] @ K[2048,1024]^T -> bf16 exp-weights + lsum
  gemm_sc<<<dim3(16, 16, 4), blk, 0, stream>>>(
      Q, Kb, 1024, 1024, 2048, 1024,
      2048L * 1024, 2048L * 1024, 2048L * 2048,
      lsum, Sc);

  // PV: per batch Sc[2048,2048](bf16) @ Vt[1024,2048]^T -> out fp32, /lsum
  // r11: 128x64 tile, 1024 blocks to fill 4-deep residency.
  gemm_pv<<<dim3(16, 16, 4), blk, 0, stream>>>(
      Sc, Vt, out, 2048, 2048, 1024, 2048,
      2048L * 2048, 1024L * 2048, 2048L * 1024,
      lsum);
}